// Round 8
// baseline (120.943 us; speedup 1.0000x reference)
//
#include <hip/hip_runtime.h>

// SliceNApply: bilateral-grid trilinear slice + per-pixel 3x4 affine apply.
// FP32 tensors. B=4, C=12, D=8, Hg=Wg=16, H=W=1024.
//
// R14: register-staged LDS pipeline (T14 async-split applied to ds_read).
//   Post-mortem R9-R13: occupancy moves (4->8 wave band, tile splits,
//   caps) never beat R9's 117.5 -> wave count is not the limiter. Model:
//   kernel ~33.5us == LDS pipe (15.4) + HBM (17.8) SERIAL because each
//   iteration issues its 12 ds_read_b128 and consumes them in the same
//   body (lgkmcnt exposed under 16-wave queue contention every iter).
//   Fix: 12 named uint4 hold iter-i LDS data; body consumes chunk k
//   (12 dot2) then refills chunk k in place with iter-i+1 reads at
//   s_next (computed from 2-deep guide prefetch). Each read now has
//   ~200+ cyc of independent dot2s before its consumer -> lgkmcnt(N)
//   pass-through, LDS overlaps HBM. fr 1-deep prefetch; tail guarded.
//   Per-block accumulator order unchanged (corner 0..3 per output block)
//   -> bit-identical rounding to R13.
//   Kept: f16 z-pair pack + v_dot2_f32_f16 (R8), 64x32 tile + 6-cell
//   staging + ZSTRIDE 100 (R10, ==4 mod 32 conflict-free), 1 px/lane,
//   all named scalars (rule #20), launch_bounds(256,4) (R11 lesson:
//   never cap below need).

#define ZSTRIDE 100   // 6 cells * 12 ch = 72 dwords + 28 pad (100 % 32 == 4)

using half2v = decltype(__builtin_amdgcn_cvt_pkrtz(0.0f, 0.0f));

static __device__ __forceinline__ half2v pkrtz(float lo, float hi) {
    return __builtin_amdgcn_cvt_pkrtz(lo, hi);   // v_cvt_pkrtz_f16_f32
}
static __device__ __forceinline__ half2v u2h2(unsigned int u) {
    return __builtin_bit_cast(half2v, u);
}
static __device__ __forceinline__ unsigned int h2u(half2v h) {
    return __builtin_bit_cast(unsigned int, h);
}

#if __has_builtin(__builtin_amdgcn_fdot2)
#define DOT2(d, wp, acc) __builtin_amdgcn_fdot2(u2h2(d), (wp), (acc), false)
#else
static __device__ __forceinline__ float dot2_sw(unsigned int d, half2v wp, float acc) {
    half2v h = u2h2(d);
    return fmaf((float)wp.x, (float)h.x, fmaf((float)wp.y, (float)h.y, acc));
}
#define DOT2(d, wp, acc) dot2_sw((d), (wp), (acc))
#endif

// consume one corner chunk (3 uint4 = 12 channels) into the 12 accumulators
#define CONSUME(qa, qb, qc, wp)                                   \
    aA0 = DOT2((qa).x, (wp), aA0); aA1 = DOT2((qa).y, (wp), aA1); \
    aA2 = DOT2((qa).z, (wp), aA2); aA3 = DOT2((qa).w, (wp), aA3); \
    aB0 = DOT2((qb).x, (wp), aB0); aB1 = DOT2((qb).y, (wp), aB1); \
    aB2 = DOT2((qb).z, (wp), aB2); aB3 = DOT2((qb).w, (wp), aB3); \
    aC0 = DOT2((qc).x, (wp), aC0); aC1 = DOT2((qc).y, (wp), aC1); \
    aC2 = DOT2((qc).z, (wp), aC2); aC3 = DOT2((qc).w, (wp), aC3);

#define REFILL(qa, qb, qc, cof)                                        \
    qa = *reinterpret_cast<const uint4*>(sbn + (cof));                 \
    qb = *reinterpret_cast<const uint4*>(sbn + (cof) + 4);             \
    qc = *reinterpret_cast<const uint4*>(sbn + (cof) + 8);

__global__ __launch_bounds__(256, 4) void slice_apply(
    const float* __restrict__ grid,   // [4][12][8][16][16]
    const float* __restrict__ guide,  // [4][1][1024][1024]
    const float* __restrict__ fr,     // [4][3][1024][1024]
    float* __restrict__ out)          // [4][3][1024][1024]
{
    __shared__ __align__(16) unsigned int lds[8 * ZSTRIDE];

    const int b     = blockIdx.y;
    const int tileX = blockIdx.x & 15;   // 0..15  (64-px columns)
    const int tileY = blockIdx.x >> 4;   // 0..31  (32-px rows)
    const int t     = threadIdx.x;

    // wave = quadrant (32x16 px); lane -> 1 px: 32 x-lanes, 2 sub-rows,
    // 8 iterations of 2 rows each.
    const int w   = t >> 6;
    const int l   = t & 63;
    const int by  = w >> 1;          // wave-uniform (row half)
    const int bx  = w & 1;           // wave-uniform (col half)
    const int lx  = l & 31;          // x within quadrant
    const int sub = l >> 5;          // sub-row 0..1

    const int tx  = bx * 32 + lx;                       // tile-local x
    const int xg  = tileX * 64 + tx;                    // global x
    const int y0  = tileY * 32 + by * 16 + sub;         // iter-0 global y
    int gofs = (b * 1024 + y0) * 1024 + xg;
    int fofs = ((b * 3) * 1024 + y0) * 1024 + xg;

    // ---- prologue pixel loads BEFORE staging (hide under stage+barrier)
    float gcur = guide[gofs];                 // g[0]
    float gnx  = guide[gofs + 2048];          // g[1]
    float f0c  = fr[fofs];
    float f1c  = fr[fofs + 1048576];
    float f2c  = fr[fofs + 2097152];

    // ---- stage 2x3-cell grid slice into LDS, z-pair packed as f16x2 ----
    {
        const int yodd = tileY & 1;
        const int fy0  = (tileY >> 1) - 1 + yodd;       // uniform per tile
        const int ry0  = min(max(fy0, 0), 15);
        const int ry1  = min(max(fy0 + 1, 0), 15);
        const int px0  = min(max(tileX - 1, 0), 15);
        const int px1  = tileX;
        const int px2  = min(tileX + 1, 15);
        for (int e = t; e < 8 * 6 * 12; e += 256) {
            const int c    = e % 12;
            const int cell = (e / 12) % 6;
            const int s    = e / 72;
            const int s2   = min(s + 1, 7);
            const int yr   = cell / 3;   // 0,1
            const int xc   = cell % 3;
            const int ry = yr ? ry1 : ry0;
            const int rx = (xc == 0) ? px0 : ((xc == 1) ? px1 : px2);
            const int cb = (b * 12 + c) * 8;
            const int sp = ry * 16 + rx;
            const float lo = grid[(cb + s)  * 256 + sp];
            const float hi = grid[(cb + s2) * 256 + sp];
            lds[s * ZSTRIDE + cell * 12 + c] = h2u(pkrtz(lo, hi));
        }
    }
    __syncthreads();

    const float wx = ((float)tx + 0.5f) * 0.015625f + (0.5f - (float)bx);
    const float u1 = wx, u0 = 1.0f - wx;

    // corner dword offsets (both y-cell rows shared by whole tile)
    const int cof0 = (0 + bx) * 12;      // (yrow0, xcol bx)
    const int cof1 = (1 + bx) * 12;      // (yrow0, xcol bx+1)
    const int cof2 = (3 + bx) * 12;      // (yrow1, xcol bx)
    const int cof3 = (4 + bx) * 12;      // (yrow1, xcol bx+1)

    const float wyb = (tileY & 1) ? 0.0f : 0.5f;

    // ---- iter-0 z-select + LDS fill (12 named uint4, chunked by corner)
    uint4 q0a, q0b, q0c, q1a, q1b, q1c, q2a, q2b, q2c, q3a, q3b, q3c;
    float wzc;
    {
        const float gz = gcur * 8.0f - 0.5f;
        int s = (int)floorf(gz);
        s = min(max(s, 0), 7);
        wzc = fmaxf(gz - (float)s, 0.0f);
        const unsigned int* sbn = &lds[s * ZSTRIDE];
        REFILL(q0a, q0b, q0c, cof0)
        REFILL(q1a, q1b, q1c, cof1)
        REFILL(q2a, q2b, q2c, cof2)
        REFILL(q3a, q3b, q3c, cof3)
    }

    float gn2 = 0.f, fn0 = 0.f, fn1 = 0.f, fn2 = 0.f;

    #pragma unroll
    for (int i = 0; i < 8; ++i) {
        // ---- issue next global loads (guide 2-deep, fr 1-deep) ----
        if (i < 6) gn2 = guide[gofs + 4096];        // g[i+2]
        if (i < 7) {
            fn0 = fr[fofs + 2048];                  // fr[i+1]
            fn1 = fr[fofs + 2048 + 1048576];
            fn2 = fr[fofs + 2048 + 2097152];
        }

        // ---- z-select for NEXT iteration (address for the refills) ----
        float wzn = 0.f;
        const unsigned int* sbn = lds;              // safe dummy
        if (i < 7) {
            const float gz = gnx * 8.0f - 0.5f;
            int s = (int)floorf(gz);
            s = min(max(s, 0), 7);
            wzn = fmaxf(gz - (float)s, 0.0f);
            sbn = &lds[s * ZSTRIDE];
        }

        // ---- current iteration weights ----
        const int ly = by * 16 + i * 2 + sub;       // tile-local y (0..31)
        const float wy = ((float)ly + 0.5f) * 0.015625f + wyb;
        const float v1 = wy, v0 = 1.0f - wy;
        const float zl = 1.0f - wzc, zh = wzc;
        const float w00 = v0 * u0, w01 = v0 * u1;
        const float w10 = v1 * u0, w11 = v1 * u1;
        const half2v wp0 = pkrtz(w00 * zl, w00 * zh);
        const half2v wp1 = pkrtz(w01 * zl, w01 * zh);
        const half2v wp2 = pkrtz(w10 * zl, w10 * zh);
        const half2v wp3 = pkrtz(w11 * zl, w11 * zh);

        // ---- consume chunk k (iter i) then refill chunk k (iter i+1) ----
        float aA0 = 0.f, aA1 = 0.f, aA2 = 0.f, aA3 = 0.f;
        float aB0 = 0.f, aB1 = 0.f, aB2 = 0.f, aB3 = 0.f;
        float aC0 = 0.f, aC1 = 0.f, aC2 = 0.f, aC3 = 0.f;

        CONSUME(q0a, q0b, q0c, wp0)
        if (i < 7) { REFILL(q0a, q0b, q0c, cof0) }
        CONSUME(q1a, q1b, q1c, wp1)
        if (i < 7) { REFILL(q1a, q1b, q1c, cof1) }
        CONSUME(q2a, q2b, q2c, wp2)
        if (i < 7) { REFILL(q2a, q2b, q2c, cof2) }
        CONSUME(q3a, q3b, q3c, wp3)
        if (i < 7) { REFILL(q3a, q3b, q3c, cof3) }

        // ---- apply + store ----
        const float o0 = fmaf(aA0, f0c, fmaf(aA1, f1c, fmaf(aA2, f2c, aA3)));
        const float o1 = fmaf(aB0, f0c, fmaf(aB1, f1c, fmaf(aB2, f2c, aB3)));
        const float o2 = fmaf(aC0, f0c, fmaf(aC1, f1c, fmaf(aC2, f2c, aC3)));
        out[fofs]           = o0;
        out[fofs + 1048576] = o1;
        out[fofs + 2097152] = o2;

        // ---- rotate pipeline state ----
        gnx = gn2;
        f0c = fn0; f1c = fn1; f2c = fn2;
        wzc = wzn;
        gofs += 2048;   // 2 rows per iteration
        fofs += 2048;
    }
}

extern "C" void kernel_launch(void* const* d_in, const int* in_sizes, int n_in,
                              void* d_out, int out_size, void* d_ws, size_t ws_size,
                              hipStream_t stream) {
    const float* grid  = (const float*)d_in[0];
    const float* guide = (const float*)d_in[1];
    const float* fr    = (const float*)d_in[2];
    float* out = (float*)d_out;

    dim3 g(512, 4);   // 16x32 tiles of 64x32 px, 4 batches
    dim3 blk(256);
    hipLaunchKernelGGL(slice_apply, g, blk, 0, stream, grid, guide, fr, out);
}

// Round 9
// 117.510 us; speedup vs baseline: 1.0292x; 1.0292x over previous
//
#include <hip/hip_runtime.h>

// SliceNApply: bilateral-grid trilinear slice + per-pixel 3x4 affine apply.
// FP32 tensors. B=4, C=12, D=8, Hg=Wg=16, H=W=1024.
//
// R15: restore R9 — the session's best measured config (117.5 us).
//   Post-mortem of the full arc: R8 fdot2 (-5.1), R9 prefetch+2px/lane
//   (-2.6) were the real levers. R11-R13 occupancy moves (tile split,
//   launch_bounds 4/5/6/8, 64-VGPR band) all regressed or were neutral;
//   R14's register-staged LDS pipeline was neutral -> the residual
//   LDS-pipe(15.4us) / HBM(~19us) serialization is insensitive to
//   source-level scheduling. Per-px work is irreducible: 192B LDS gather
//   (12 x ds_read_b128, minimal for 4 corners x 12ch f16-z-pairs) + 28B
//   HBM. e2e dur_us is dominated by ~84us of harness fills at ~80% HBM
//   peak. This is the terminal configuration.
//
// R9: break the per-iteration guide->s->LDS dependency chain.
//   (a) explicit 1-iter software prefetch of guide/fr; (b) 2 px/lane
//   via float2 loads/stores -> 8 chains instead of 16, ~2x busy work per
//   chain, half the global instructions, 8B/lane coalescing sweet spot.
//   __launch_bounds__(256,4): VGPR cap 128, no spills.
//   Kept (verified R2-R8): f16 z-pair pack + v_dot2_f32_f16, 12
//   ds_read_b128/px, quadrant waves + ZSTRIDE=132 (bank = 4s+cof mod 32,
//   conflict-free), zero local arrays / all-scalar compute (scratch-proof).

#define ZSTRIDE 132   // 9 cells * 12 ch = 108 dwords + 24 pad (132 % 32 == 4)

using half2v = decltype(__builtin_amdgcn_cvt_pkrtz(0.0f, 0.0f));

static __device__ __forceinline__ half2v pkrtz(float lo, float hi) {
    return __builtin_amdgcn_cvt_pkrtz(lo, hi);   // v_cvt_pkrtz_f16_f32
}
static __device__ __forceinline__ half2v u2h2(unsigned int u) {
    return __builtin_bit_cast(half2v, u);
}
static __device__ __forceinline__ unsigned int h2u(half2v h) {
    return __builtin_bit_cast(unsigned int, h);
}

#if __has_builtin(__builtin_amdgcn_fdot2)
#define DOT2(d, wp, acc) __builtin_amdgcn_fdot2(u2h2(d), (wp), (acc), false)
#else
// fallback: mixed-precision fma (compiler forms v_fma_mix_f32)
static __device__ __forceinline__ float dot2_sw(unsigned int d, half2v wp, float acc) {
    half2v h = u2h2(d);
    return fmaf((float)wp.x, (float)h.x, fmaf((float)wp.y, (float)h.y, acc));
}
#define DOT2(d, wp, acc) dot2_sw((d), (wp), (acc))
#endif

// one corner's 4-channel dual-z dot-accumulate (all scalar refs)
static __device__ __forceinline__ void corner_dot(
    const unsigned int* __restrict__ cp, half2v wp,
    float& a0, float& a1, float& a2, float& a3)
{
    const uint4 d = *reinterpret_cast<const uint4*>(cp);
    a0 = DOT2(d.x, wp, a0);
    a1 = DOT2(d.y, wp, a1);
    a2 = DOT2(d.z, wp, a2);
    a3 = DOT2(d.w, wp, a3);
}

// full per-pixel slice + apply; everything scalar (scratch-proof)
static __device__ __forceinline__ void px_eval(
    const unsigned int* __restrict__ lds,
    float g, float f0, float f1, float f2,
    float u0, float u1, float v0, float v1,
    int cof0, int cof1, int cof2, int cof3,
    float& o0, float& o1, float& o2)
{
    const float gz = g * 8.0f - 0.5f;
    int s = (int)floorf(gz);
    s = min(max(s, 0), 7);
    const float wz = fmaxf(gz - (float)s, 0.0f);
    const float zl = 1.0f - wz, zh = wz;
    const unsigned int* sb = &lds[s * ZSTRIDE];

    const float w00 = v0 * u0, w01 = v0 * u1;
    const float w10 = v1 * u0, w11 = v1 * u1;
    const half2v wp0 = pkrtz(w00 * zl, w00 * zh);
    const half2v wp1 = pkrtz(w01 * zl, w01 * zh);
    const half2v wp2 = pkrtz(w10 * zl, w10 * zh);
    const half2v wp3 = pkrtz(w11 * zl, w11 * zh);

    {
        float a0 = 0.f, a1 = 0.f, a2 = 0.f, a3 = 0.f;
        corner_dot(sb + cof0, wp0, a0, a1, a2, a3);
        corner_dot(sb + cof1, wp1, a0, a1, a2, a3);
        corner_dot(sb + cof2, wp2, a0, a1, a2, a3);
        corner_dot(sb + cof3, wp3, a0, a1, a2, a3);
        o0 = fmaf(a0, f0, fmaf(a1, f1, fmaf(a2, f2, a3)));
    }
    {
        float a0 = 0.f, a1 = 0.f, a2 = 0.f, a3 = 0.f;
        corner_dot(sb + cof0 + 4, wp0, a0, a1, a2, a3);
        corner_dot(sb + cof1 + 4, wp1, a0, a1, a2, a3);
        corner_dot(sb + cof2 + 4, wp2, a0, a1, a2, a3);
        corner_dot(sb + cof3 + 4, wp3, a0, a1, a2, a3);
        o1 = fmaf(a0, f0, fmaf(a1, f1, fmaf(a2, f2, a3)));
    }
    {
        float a0 = 0.f, a1 = 0.f, a2 = 0.f, a3 = 0.f;
        corner_dot(sb + cof0 + 8, wp0, a0, a1, a2, a3);
        corner_dot(sb + cof1 + 8, wp1, a0, a1, a2, a3);
        corner_dot(sb + cof2 + 8, wp2, a0, a1, a2, a3);
        corner_dot(sb + cof3 + 8, wp3, a0, a1, a2, a3);
        o2 = fmaf(a0, f0, fmaf(a1, f1, fmaf(a2, f2, a3)));
    }
}

__global__ __launch_bounds__(256, 4) void slice_apply(
    const float* __restrict__ grid,   // [4][12][8][16][16]
    const float* __restrict__ guide,  // [4][1][1024][1024]
    const float* __restrict__ fr,     // [4][3][1024][1024]
    float* __restrict__ out)          // [4][3][1024][1024]
{
    __shared__ __align__(16) unsigned int lds[8 * ZSTRIDE];

    const int b     = blockIdx.y;
    const int tileX = blockIdx.x & 15;
    const int tileY = blockIdx.x >> 4;
    const int t     = threadIdx.x;

    // ---- stage grid slice into LDS, z-pair packed as f16x2 ----
    {
        const int py0 = min(max(tileY - 1, 0), 15);
        const int py1 = tileY;
        const int py2 = min(tileY + 1, 15);
        const int px0 = min(max(tileX - 1, 0), 15);
        const int px1 = tileX;
        const int px2 = min(tileX + 1, 15);
        for (int e = t; e < 8 * 9 * 12; e += 256) {
            const int c    = e % 12;
            const int cell = (e / 12) % 9;
            const int s    = e / 108;
            const int s2   = min(s + 1, 7);
            const int gy3  = cell / 3;
            const int gx3  = cell % 3;
            const int ry = (gy3 == 0) ? py0 : ((gy3 == 1) ? py1 : py2);
            const int rx = (gx3 == 0) ? px0 : ((gx3 == 1) ? px1 : px2);
            const int cb = (b * 12 + c) * 8;
            const int sp = ry * 16 + rx;
            const float lo = grid[(cb + s)  * 256 + sp];
            const float hi = grid[(cb + s2) * 256 + sp];
            lds[s * ZSTRIDE + cell * 12 + c] = h2u(pkrtz(lo, hi));
        }
    }
    __syncthreads();

    // wave = quadrant (32x32 px); lane -> 2 adjacent-x px:
    //   16 lanes span x (float2), 4 sub-rows per iter, 8 iters.
    const int w   = t >> 6;
    const int l   = t & 63;
    const int by  = w >> 1;          // wave-uniform
    const int bx  = w & 1;           // wave-uniform
    const int lx2 = l & 15;          // x-pair index within quadrant
    const int sub = l >> 4;          // sub-row 0..3

    const int txA = bx * 32 + lx2 * 2;                  // tile-local x of px A
    const int xg  = tileX * 64 + txA;                   // global x (even)
    const float wxA = ((float)txA + 0.5f) * 0.015625f + (0.5f - (float)bx);
    const float wxB = wxA + 0.015625f;
    const float u1A = wxA, u0A = 1.0f - wxA;
    const float u1B = wxB, u0B = 1.0f - wxB;

    // corner dword offsets: four named scalars (NOT an array)
    const int cof0 = ((by + 0) * 3 + (bx + 0)) * 12;
    const int cof1 = ((by + 0) * 3 + (bx + 1)) * 12;
    const int cof2 = ((by + 1) * 3 + (bx + 0)) * 12;
    const int cof3 = ((by + 1) * 3 + (bx + 1)) * 12;

    // iter-0 addresses (row ly0 = by*32 + sub)
    const int y0   = tileY * 64 + by * 32 + sub;
    int gofs = (b * 1024 + y0) * 1024 + xg;
    int fofs = ((b * 3) * 1024 + y0) * 1024 + xg;

    // ---- prologue: load iteration 0 ----
    float2 gv  = *reinterpret_cast<const float2*>(guide + gofs);
    float2 f0v = *reinterpret_cast<const float2*>(fr + fofs);
    float2 f1v = *reinterpret_cast<const float2*>(fr + fofs + 1048576);
    float2 f2v = *reinterpret_cast<const float2*>(fr + fofs + 2097152);

    #pragma unroll
    for (int i = 0; i < 8; ++i) {
        // ---- issue next iteration's loads first (latency hiding) ----
        float2 gn = gv, f0n = f0v, f1n = f1v, f2n = f2v;
        if (i < 7) {
            const int gofs_n = gofs + 4 * 1024;   // +4 rows
            const int fofs_n = fofs + 4 * 1024;
            gn  = *reinterpret_cast<const float2*>(guide + gofs_n);
            f0n = *reinterpret_cast<const float2*>(fr + fofs_n);
            f1n = *reinterpret_cast<const float2*>(fr + fofs_n + 1048576);
            f2n = *reinterpret_cast<const float2*>(fr + fofs_n + 2097152);
        }

        // ---- compute current iteration ----
        const int ly = by * 32 + i * 4 + sub;     // tile-local y
        const float wy = ((float)ly + 0.5f) * 0.015625f + (0.5f - (float)by);
        const float v1 = wy, v0 = 1.0f - wy;

        float oA0, oA1, oA2, oB0, oB1, oB2;
        px_eval(lds, gv.x, f0v.x, f1v.x, f2v.x, u0A, u1A, v0, v1,
                cof0, cof1, cof2, cof3, oA0, oA1, oA2);
        px_eval(lds, gv.y, f0v.y, f1v.y, f2v.y, u0B, u1B, v0, v1,
                cof0, cof1, cof2, cof3, oB0, oB1, oB2);

        *reinterpret_cast<float2*>(out + fofs)           = make_float2(oA0, oB0);
        *reinterpret_cast<float2*>(out + fofs + 1048576) = make_float2(oA1, oB1);
        *reinterpret_cast<float2*>(out + fofs + 2097152) = make_float2(oA2, oB2);

        // ---- rotate ----
        gofs += 4 * 1024;
        fofs += 4 * 1024;
        gv = gn; f0v = f0n; f1v = f1n; f2v = f2n;
    }
}

extern "C" void kernel_launch(void* const* d_in, const int* in_sizes, int n_in,
                              void* d_out, int out_size, void* d_ws, size_t ws_size,
                              hipStream_t stream) {
    const float* grid  = (const float*)d_in[0];
    const float* guide = (const float*)d_in[1];
    const float* fr    = (const float*)d_in[2];
    float* out = (float*)d_out;

    dim3 g(256, 4);   // 16x16 tiles of 64x64 px, 4 batches
    dim3 blk(256);
    hipLaunchKernelGGL(slice_apply, g, blk, 0, stream, grid, guide, fr, out);
}